// Round 1
// baseline (182.615 us; speedup 1.0000x reference)
//
#include <hip/hip_runtime.h>
#include <math.h>
#include <stdint.h>

#define B 4
#define S 4096
#define E 768
#define H 64
#define NMAT 192   // 3*64 output columns (q|k|v)

typedef _Float16 half_t;
typedef __attribute__((ext_vector_type(8))) _Float16 half8;
typedef __attribute__((ext_vector_type(4))) _Float16 half4;
typedef __attribute__((ext_vector_type(2))) _Float16 half2v;
typedef __attribute__((ext_vector_type(4))) float f32x4;
typedef __attribute__((ext_vector_type(16))) float f32x16;
typedef __attribute__((ext_vector_type(4))) unsigned int uint4v;

#define LOG2E 1.4426950408889634f

// ---------------- W prep: fp16 Dekker split ----------------
// Wst layout: [kstep 24][n 192][part 2][32]  (n = mat*64+h, part 0=hi 1=lo)
__global__ __launch_bounds__(256) void wprep_kernel(
    const float* __restrict__ Wq, const float* __restrict__ Wk,
    const float* __restrict__ Wv, half_t* __restrict__ Wst)
{
    int gid = blockIdx.x * 256 + threadIdx.x;     // 0..147455
    int m = gid / (H * E);
    int rem = gid - m * (H * E);
    int h = rem / E;
    int e = rem - h * E;
    const float* W = (m == 0) ? Wq : (m == 1) ? Wk : Wv;
    float val = W[h * E + e];
    half_t hi = (half_t)val;
    float lo = val - (float)hi;
    int n = m * H + h;
    int ks = e >> 5, kk = e & 31;
    size_t base = ((size_t)(ks * NMAT + n) * 2) * 32 + kk;
    Wst[base]      = hi;
    Wst[base + 32] = (half_t)lo;
}

// ---------------- Projection: fp16-split MFMA GEMM ----------------
// grid 512 x 512 thr (8 waves = msub 2 x nsplit 4), 32 M-rows/block.
// q is scaled by 1/8 here (exact pow2) so flash's scores come out as qk/8.
#define WROW 72
__global__ __launch_bounds__(512, 4) void proj_kernel(
    const float* __restrict__ x, const half_t* __restrict__ Wst,
    half_t* __restrict__ qhi, half_t* __restrict__ qlo,
    half_t* __restrict__ khi, half_t* __restrict__ klo,
    half_t* __restrict__ vt)
{
    __shared__ __align__(16) half_t W_s[2][NMAT * WROW];  // 2 x 27648 B

    const int t = threadIdx.x;
    const int w = t >> 6, lane = t & 63;
    const int col = lane & 15, quad = lane >> 4;
    const int nsplit = w & 3, msub = w >> 2;
    const int mrow = blockIdx.x * 32 + msub * 16 + col;

    half8 stg[4];
    f32x4 acc[3];
    #pragma unroll
    for (int i = 0; i < 3; ++i) acc[i] = (f32x4){0.f, 0.f, 0.f, 0.f};

    // prologue: stage ks=0
    if (t < 384) {
        const half_t* src = Wst + ((size_t)0 * NMAT * 2 + t) * 32;
        #pragma unroll
        for (int i = 0; i < 4; ++i) stg[i] = *(const half8*)(src + i * 8);
        half_t* dst = &W_s[0][(t >> 1) * WROW + (t & 1) * 32];
        #pragma unroll
        for (int i = 0; i < 4; ++i) *(half8*)(dst + i * 8) = stg[i];
    }
    __syncthreads();

    for (int ks = 0; ks < 24; ++ks) {
        const int cur = ks & 1;
        if (ks < 23 && t < 384) {
            const half_t* src = Wst + ((size_t)(ks + 1) * NMAT * 2 + t) * 32;
            #pragma unroll
            for (int i = 0; i < 4; ++i) stg[i] = *(const half8*)(src + i * 8);
        }

        // A fragment: x fp32 -> f16 hi/lo
        const float* xp = x + (size_t)mrow * E + ks * 32 + quad * 8;
        float4 xa = *(const float4*)xp;
        float4 xb = *(const float4*)(xp + 4);
        float xv[8] = {xa.x, xa.y, xa.z, xa.w, xb.x, xb.y, xb.z, xb.w};
        half8 ah, al;
        #pragma unroll
        for (int j = 0; j < 8; ++j) {
            half_t hi = (half_t)xv[j];
            ah[j] = hi;
            al[j] = (half_t)(xv[j] - (float)hi);
        }

        #pragma unroll
        for (int ci = 0; ci < 3; ++ci) {
            int c = nsplit + ci * 4;
            const half_t* wr = &W_s[cur][(c * 16 + col) * WROW];
            half8 bh = *(const half8*)(wr + quad * 8);
            acc[ci] = __builtin_amdgcn_mfma_f32_16x16x32_f16(ah, bh, acc[ci], 0, 0, 0);
            if (ci < 2) {
                half8 bl = *(const half8*)(wr + 32 + quad * 8);
                acc[ci] = __builtin_amdgcn_mfma_f32_16x16x32_f16(al, bh, acc[ci], 0, 0, 0);
                acc[ci] = __builtin_amdgcn_mfma_f32_16x16x32_f16(ah, bl, acc[ci], 0, 0, 0);
            }
        }

        if (ks < 23 && t < 384) {
            half_t* dst = &W_s[cur ^ 1][(t >> 1) * WROW + (t & 1) * 32];
            #pragma unroll
            for (int i = 0; i < 4; ++i) *(half8*)(dst + i * 8) = stg[i];
        }
        __syncthreads();
    }

    // Epilogue. C-layout (16x16): row = quad*4+r, col = lane&15.
    const int srow0 = blockIdx.x * 32 + msub * 16 + quad * 4;
    const int hcol = nsplit * 16 + col;
    #pragma unroll
    for (int r = 0; r < 4; ++r) {
        int srow = srow0 + r;
        float vq = acc[0][r] * 0.125f;        // fold 1/sqrt(H) scale into q
        half_t hq = (half_t)vq;
        qhi[(size_t)srow * H + hcol] = hq;
        qlo[(size_t)srow * H + hcol] = (half_t)(vq - (float)hq);
        float vk = acc[1][r];
        half_t hk = (half_t)vk;
        khi[(size_t)srow * H + hcol] = hk;
        klo[(size_t)srow * H + hcol] = (half_t)(vk - (float)hk);
    }
    {   // v transposed [b][dim][S]
        half4 pk;
        #pragma unroll
        for (int r = 0; r < 4; ++r) pk[r] = (half_t)acc[2][r];
        int bb = srow0 >> 12, s0 = srow0 & (S - 1);
        *(half4*)(vt + ((size_t)(bb * H + hcol)) * S + s0) = pk;
    }
}

// ---------------- Flash attention v2 ----------------
// grid 512 x 256 thr. Block: 32 q-rows, 4 waves = 4 key-slices of a 128-key tile.
// LDS 64 KB (dbuf x (Khi 16K | Klo 16K)) -> 2 independent blocks/CU.
// K staged via global_load_lds (pre-swizzled source, linear LDS dest).
// V fragments read directly from L2 (vt is [b][dim][S], 16B contiguous).
// Swapped QK^T (mfma(K,Q)) keeps P in registers: cvt_pkrtz + permlane32_swap
// builds PV A-fragments with no LDS round trip.
__device__ __forceinline__ void gload_lds16(const void* g, void* l) {
    __builtin_amdgcn_global_load_lds(
        (const __attribute__((address_space(1))) unsigned int*)g,
        (__attribute__((address_space(3))) unsigned int*)l, 16, 0, 0);
}

__global__ __launch_bounds__(256, 2) void flash_kernel(
    const half_t* __restrict__ qhi, const half_t* __restrict__ qlo,
    const half_t* __restrict__ khi, const half_t* __restrict__ klo,
    const half_t* __restrict__ vt, float* __restrict__ out)
{
    __shared__ __align__(16) char smem[65536];   // buf0 32K | buf1 32K

    const int t = threadIdx.x;
    const int w = t >> 6, lane = t & 63;          // w = key-slice 0..3
    const int n32 = lane & 31, l5 = lane >> 5;

    // XCD-aware swizzle: blocks on XCD x serve batch x>>1 (K/V fits its L2)
    const int bid = blockIdx.x;
    const int b = (bid & 7) >> 1;
    const int qt = ((bid >> 3) << 1) | (bid & 1); // 0..127
    const int qrow0 = b * S + qt * 32;

    const half_t* kh_g = khi + (size_t)b * S * H;
    const half_t* kl_g = klo + (size_t)b * S * H;
    const half_t* vt_g = vt + (size_t)b * H * S;

    // Q as MFMA B-fragment: n = q-row = lane&31, k = l5*8+j  (4 k-steps, hi/lo)
    half8 qh[4], ql[4];
    #pragma unroll
    for (int ks = 0; ks < 4; ++ks) {
        size_t off = (size_t)(qrow0 + n32) * H + ks * 16 + l5 * 8;
        qh[ks] = *(const half8*)(qhi + off);
        ql[ks] = *(const half8*)(qlo + off);
    }

    // stage one 128-key tile: Khi (16 KB) + Klo (16 KB), 8 x 16B per thread.
    // source pre-swizzled (chunk c at pos c^(key&7)) so LDS dest is linear.
    auto stage = [&](int kt, int buf) {
        char* base = smem + buf * 32768;
        #pragma unroll
        for (int i = 0; i < 8; ++i) {
            int f2 = (i & 3) * 256 + t;           // chunk id within section
            int keyl = f2 >> 3;
            int c = (f2 & 7) ^ (keyl & 7);
            const half_t* g = (i < 4 ? kh_g : kl_g)
                            + ((size_t)(kt * 128 + keyl)) * H + c * 8;
            gload_lds16(g, base + (i < 4 ? 0 : 16384) + f2 * 16);
        }
    };

    stage(0, 0);

    f32x16 Oa, Ob;
    #pragma unroll
    for (int r = 0; r < 16; ++r) { Oa[r] = 0.f; Ob[r] = 0.f; }
    float lacc = 0.f;

    const int keyl = w * 32 + n32;                // this lane's key in the tile
    __syncthreads();

    for (int kt = 0; kt < 32; ++kt) {
        const int cur = kt & 1;

        // V B-frags for the CURRENT tile, direct from global (L2-resident).
        // Issued before the stage so the compiler can wait vmcnt(8), not 0.
        half8 vf00, vf10, vf01, vf11;
        {
            const half_t* vp = vt_g + (size_t)n32 * S + kt * 128 + w * 32 + l5 * 8;
            vf00 = *(const half8*)(vp);            // ks2=0, dims 0..31
            vf10 = *(const half8*)(vp + 16);       // ks2=1, dims 0..31
            vf01 = *(const half8*)(vp + 32 * S);   // ks2=0, dims 32..63
            vf11 = *(const half8*)(vp + 32 * S + 16);
        }

        if (kt < 31) stage(kt + 1, cur ^ 1);

        half_t* khs = (half_t*)(smem + cur * 32768);
        half_t* kls = khs + 8192;

        // ---- QK^T swapped: acc = K*Q^T, lane n32 = q-row, regs = keys ----
        f32x16 acc;
        #pragma unroll
        for (int r = 0; r < 16; ++r) acc[r] = 0.f;
        __builtin_amdgcn_s_setprio(1);
        #pragma unroll
        for (int ks = 0; ks < 4; ++ks) {
            int phys = ((ks * 2 + l5) ^ (keyl & 7)) * 8;
            half8 bh = *(const half8*)(khs + keyl * 64 + phys);
            half8 bl = *(const half8*)(kls + keyl * 64 + phys);
            acc = __builtin_amdgcn_mfma_f32_32x32x16_f16(bh, qh[ks], acc, 0, 0, 0);
            acc = __builtin_amdgcn_mfma_f32_32x32x16_f16(bh, ql[ks], acc, 0, 0, 0);
            acc = __builtin_amdgcn_mfma_f32_32x32x16_f16(bl, qh[ks], acc, 0, 0, 0);
        }
        __builtin_amdgcn_s_setprio(0);

        // ---- fixed-max softmax, P stays in registers ----
        // key(r) = (r&3) + 8*(r>>2) + 4*l5  (acc already = qk/8)
        unsigned int h0[4], h1[4];
        #pragma unroll
        for (int m = 0; m < 4; ++m) {
            float p0 = exp2f((floorf(acc[4 * m + 0]) - 8.0f) * LOG2E);
            float p1 = exp2f((floorf(acc[4 * m + 1]) - 8.0f) * LOG2E);
            float p2 = exp2f((floorf(acc[4 * m + 2]) - 8.0f) * LOG2E);
            float p3 = exp2f((floorf(acc[4 * m + 3]) - 8.0f) * LOG2E);
            lacc += p0 + p1 + p2 + p3;
            h0[m] = __builtin_bit_cast(unsigned int, __builtin_amdgcn_cvt_pkrtz(p0, p1));
            h1[m] = __builtin_bit_cast(unsigned int, __builtin_amdgcn_cvt_pkrtz(p2, p3));
        }

        // ---- PV: build A-frags with permlane32_swap, no LDS ----
        __builtin_amdgcn_s_setprio(1);
        #pragma unroll
        for (int ks2 = 0; ks2 < 2; ++ks2) {
            auto s1 = __builtin_amdgcn_permlane32_swap(h0[2 * ks2], h0[2 * ks2 + 1], false, false);
            auto s2 = __builtin_amdgcn_permlane32_swap(h1[2 * ks2], h1[2 * ks2 + 1], false, false);
            uint4v pw;
            pw[0] = s1[0]; pw[1] = s2[0]; pw[2] = s1[1]; pw[3] = s2[1];
            half8 pf = __builtin_bit_cast(half8, pw);
            Oa = __builtin_amdgcn_mfma_f32_32x32x16_f16(pf, ks2 ? vf10 : vf00, Oa, 0, 0, 0);
            Ob = __builtin_amdgcn_mfma_f32_32x32x16_f16(pf, ks2 ? vf11 : vf01, Ob, 0, 0, 0);
        }
        __builtin_amdgcn_s_setprio(0);

        __syncthreads();
    }

    // ---- denominator: other 16 keys live in the opposite lane-half ----
    lacc += __shfl_xor(lacc, 32);

    // ---- combine the 4 key-slice partials via LDS (stride 68 = conflict-lite) ----
    float* Oc  = (float*)smem;                    // [4][32][68] = 34816 B
    float* l_s = (float*)(smem + 34816);          // [4][32]
    #pragma unroll
    for (int r = 0; r < 16; ++r) {
        int rowl = (r & 3) + 8 * (r >> 2) + 4 * l5;
        Oc[(w * 32 + rowl) * 68 + n32]      = Oa[r];
        Oc[(w * 32 + rowl) * 68 + 32 + n32] = Ob[r];
    }
    if (lane < 32) l_s[w * 32 + n32] = lacc;
    __syncthreads();

    {
        int row = t >> 3;            // 0..31
        int d0 = (t & 7) * 8;        // 0..56
        float den = l_s[row] + l_s[32 + row] + l_s[64 + row] + l_s[96 + row];
        float s0 = 0.f, s1 = 0.f, s2 = 0.f, s3 = 0.f;
        float s4 = 0.f, s5 = 0.f, s6 = 0.f, s7 = 0.f;
        #pragma unroll
        for (int k = 0; k < 4; ++k) {
            const float* oc = Oc + (size_t)(k * 32 + row) * 68 + d0;
            float4 a = *(const float4*)oc;
            float4 bq = *(const float4*)(oc + 4);
            s0 += a.x;  s1 += a.y;  s2 += a.z;  s3 += a.w;
            s4 += bq.x; s5 += bq.y; s6 += bq.z; s7 += bq.w;
        }
        float inv = 1.f / den;
        float4 o1 = make_float4(s0 * inv, s1 * inv, s2 * inv, s3 * inv);
        float4 o2 = make_float4(s4 * inv, s5 * inv, s6 * inv, s7 * inv);
        float* op = out + (size_t)(qrow0 + row) * H + d0;
        *(float4*)op = o1;
        *(float4*)(op + 4) = o2;
    }
}

extern "C" void kernel_launch(void* const* d_in, const int* in_sizes, int n_in,
                              void* d_out, int out_size, void* d_ws, size_t ws_size,
                              hipStream_t stream) {
    const float* x  = (const float*)d_in[0];
    const float* Wq = (const float*)d_in[1];
    const float* Wk = (const float*)d_in[2];
    const float* Wv = (const float*)d_in[3];
    float* outp = (float*)d_out;

    const size_t N = (size_t)B * S * H;          // 1,048,576
    half_t* qhi = (half_t*)d_ws;
    half_t* qlo = qhi + N;
    half_t* khi = qlo + N;
    half_t* klo = khi + N;
    half_t* vt  = klo + N;
    half_t* Wst = vt + N;                        // 294912 halves

    wprep_kernel<<<(3 * H * E) / 256, 256, 0, stream>>>(Wq, Wk, Wv, Wst);
    proj_kernel<<<(B * S) / 32, 512, 0, stream>>>(x, Wst, qhi, qlo, khi, klo, vt);
    flash_kernel<<<B * (S / 32), 256, 0, stream>>>(qhi, qlo, khi, klo, vt, outp);
}

// Round 2
// 174.948 us; speedup vs baseline: 1.0438x; 1.0438x over previous
//
#include <hip/hip_runtime.h>
#include <math.h>
#include <stdint.h>

#define B 4
#define S 4096
#define E 768
#define H 64
#define NMAT 192   // 3*64 output columns (q|k|v)

typedef _Float16 half_t;
typedef __attribute__((ext_vector_type(8))) _Float16 half8;
typedef __attribute__((ext_vector_type(4))) _Float16 half4;
typedef __attribute__((ext_vector_type(4))) float f32x4;
typedef __attribute__((ext_vector_type(16))) float f32x16;
typedef __attribute__((ext_vector_type(4))) unsigned int uint4v;

#define LOG2E 1.4426950408889634f

// ---------------- W prep: fp16 Dekker split ----------------
// Wst layout: [kstep 24][n 192][part 2][32]  (n = mat*64+h, part 0=hi 1=lo)
__global__ __launch_bounds__(256) void wprep_kernel(
    const float* __restrict__ Wq, const float* __restrict__ Wk,
    const float* __restrict__ Wv, half_t* __restrict__ Wst)
{
    int gid = blockIdx.x * 256 + threadIdx.x;     // 0..147455
    int m = gid / (H * E);
    int rem = gid - m * (H * E);
    int h = rem / E;
    int e = rem - h * E;
    const float* W = (m == 0) ? Wq : (m == 1) ? Wk : Wv;
    float val = W[h * E + e];
    half_t hi = (half_t)val;
    float lo = val - (float)hi;
    int n = m * H + h;
    int ks = e >> 5, kk = e & 31;
    size_t base = ((size_t)(ks * NMAT + n) * 2) * 32 + kk;
    Wst[base]      = hi;
    Wst[base + 32] = (half_t)lo;
}

// ---------------- Projection: fp16-split MFMA GEMM ----------------
// grid 512 x 512 thr (8 waves = msub 2 x nsplit 4), 32 M-rows/block.
// q is scaled by 1/8 here (exact pow2) so flash's scores come out as qk/8.
#define WROW 72
__global__ __launch_bounds__(512, 4) void proj_kernel(
    const float* __restrict__ x, const half_t* __restrict__ Wst,
    half_t* __restrict__ qhi, half_t* __restrict__ qlo,
    half_t* __restrict__ khi, half_t* __restrict__ klo,
    half_t* __restrict__ vt)
{
    __shared__ __align__(16) half_t W_s[2][NMAT * WROW];  // 2 x 27648 B

    const int t = threadIdx.x;
    const int w = t >> 6, lane = t & 63;
    const int col = lane & 15, quad = lane >> 4;
    const int nsplit = w & 3, msub = w >> 2;
    const int mrow = blockIdx.x * 32 + msub * 16 + col;

    half8 stg[4];
    f32x4 acc[3];
    #pragma unroll
    for (int i = 0; i < 3; ++i) acc[i] = (f32x4){0.f, 0.f, 0.f, 0.f};

    // prologue: stage ks=0
    if (t < 384) {
        const half_t* src = Wst + ((size_t)0 * NMAT * 2 + t) * 32;
        #pragma unroll
        for (int i = 0; i < 4; ++i) stg[i] = *(const half8*)(src + i * 8);
        half_t* dst = &W_s[0][(t >> 1) * WROW + (t & 1) * 32];
        #pragma unroll
        for (int i = 0; i < 4; ++i) *(half8*)(dst + i * 8) = stg[i];
    }
    __syncthreads();

    for (int ks = 0; ks < 24; ++ks) {
        const int cur = ks & 1;
        if (ks < 23 && t < 384) {
            const half_t* src = Wst + ((size_t)(ks + 1) * NMAT * 2 + t) * 32;
            #pragma unroll
            for (int i = 0; i < 4; ++i) stg[i] = *(const half8*)(src + i * 8);
        }

        // A fragment: x fp32 -> f16 hi/lo
        const float* xp = x + (size_t)mrow * E + ks * 32 + quad * 8;
        float4 xa = *(const float4*)xp;
        float4 xb = *(const float4*)(xp + 4);
        float xv[8] = {xa.x, xa.y, xa.z, xa.w, xb.x, xb.y, xb.z, xb.w};
        half8 ah, al;
        #pragma unroll
        for (int j = 0; j < 8; ++j) {
            half_t hi = (half_t)xv[j];
            ah[j] = hi;
            al[j] = (half_t)(xv[j] - (float)hi);
        }

        #pragma unroll
        for (int ci = 0; ci < 3; ++ci) {
            int c = nsplit + ci * 4;
            const half_t* wr = &W_s[cur][(c * 16 + col) * WROW];
            half8 bh = *(const half8*)(wr + quad * 8);
            acc[ci] = __builtin_amdgcn_mfma_f32_16x16x32_f16(ah, bh, acc[ci], 0, 0, 0);
            if (ci < 2) {
                half8 bl = *(const half8*)(wr + 32 + quad * 8);
                acc[ci] = __builtin_amdgcn_mfma_f32_16x16x32_f16(al, bh, acc[ci], 0, 0, 0);
                acc[ci] = __builtin_amdgcn_mfma_f32_16x16x32_f16(ah, bl, acc[ci], 0, 0, 0);
            }
        }

        if (ks < 23 && t < 384) {
            half_t* dst = &W_s[cur ^ 1][(t >> 1) * WROW + (t & 1) * 32];
            #pragma unroll
            for (int i = 0; i < 4; ++i) *(half8*)(dst + i * 8) = stg[i];
        }
        __syncthreads();
    }

    // Epilogue. C-layout (16x16): row = quad*4+r, col = lane&15.
    const int srow0 = blockIdx.x * 32 + msub * 16 + quad * 4;
    const int hcol = nsplit * 16 + col;
    #pragma unroll
    for (int r = 0; r < 4; ++r) {
        int srow = srow0 + r;
        float vq = acc[0][r] * 0.125f;        // fold 1/sqrt(H) scale into q
        half_t hq = (half_t)vq;
        qhi[(size_t)srow * H + hcol] = hq;
        qlo[(size_t)srow * H + hcol] = (half_t)(vq - (float)hq);
        float vk = acc[1][r];
        half_t hk = (half_t)vk;
        khi[(size_t)srow * H + hcol] = hk;
        klo[(size_t)srow * H + hcol] = (half_t)(vk - (float)hk);
    }
    {   // v transposed [b][dim][S]
        half4 pk;
        #pragma unroll
        for (int r = 0; r < 4; ++r) pk[r] = (half_t)acc[2][r];
        int bb = srow0 >> 12, s0 = srow0 & (S - 1);
        *(half4*)(vt + ((size_t)(bb * H + hcol)) * S + s0) = pk;
    }
}

// ---------------- Flash attention v3 ----------------
// grid 256 x 512 thr. Block: 64 q-rows, 8 waves = 2 qsub(32 rows) x 4 ksw(32 keys).
// LDS 64 KB (dbuf x (Khi 16K | Klo 16K)) -> 2 blocks/CU = 16 waves/CU = 4/SIMD.
// (Round-1 lesson: 8 waves/CU was latency-bound; more TLP is the lever.)
// K staged via global_load_lds (pre-swizzled source, linear LDS dest).
// V fragments read directly from L2 (vt is [b][dim][S]); qsub-sibling waves
// issue identical V loads -> L1 hits.
// Swapped QK^T (mfma(K,Q)) keeps P in registers: cvt_pkrtz + permlane32_swap.
__device__ __forceinline__ void gload_lds16(const void* g, void* l) {
    __builtin_amdgcn_global_load_lds(
        (const __attribute__((address_space(1))) unsigned int*)g,
        (__attribute__((address_space(3))) unsigned int*)l, 16, 0, 0);
}

__global__ __launch_bounds__(512, 4) void flash_kernel(
    const half_t* __restrict__ qhi, const half_t* __restrict__ qlo,
    const half_t* __restrict__ khi, const half_t* __restrict__ klo,
    const half_t* __restrict__ vt, float* __restrict__ out)
{
    __shared__ __align__(16) char smem[66560];   // buf0 32K | buf1 32K; epi: Oc 64K + l_s 1K

    const int t = threadIdx.x;
    const int w = t >> 6, lane = t & 63;
    const int n32 = lane & 31, l5 = lane >> 5;
    const int ksw = w & 3, qsub = w >> 2;         // 4 key-slices x 2 q-subtiles

    // XCD-aware swizzle: blocks on XCD x serve batch x>>1 (K/V fits its L2)
    const int bid = blockIdx.x;
    const int b = (bid & 7) >> 1;
    const int qt = ((bid >> 3) << 1) | (bid & 1); // 0..63
    const int qrow0 = b * S + qt * 64;

    const half_t* kh_g = khi + (size_t)b * S * H;
    const half_t* kl_g = klo + (size_t)b * S * H;
    const half_t* vt_g = vt + (size_t)b * H * S;

    // Q as MFMA B-fragment: n = q-row = lane&31, k = l5*8+j  (4 k-steps, hi/lo)
    half8 qh[4], ql[4];
    #pragma unroll
    for (int ks = 0; ks < 4; ++ks) {
        size_t off = (size_t)(qrow0 + qsub * 32 + n32) * H + ks * 16 + l5 * 8;
        qh[ks] = *(const half8*)(qhi + off);
        ql[ks] = *(const half8*)(qlo + off);
    }

    // stage one 128-key tile: Khi (16 KB) + Klo (16 KB), 4 x 16B per thread.
    // source pre-swizzled (chunk c at pos c^(key&7)) so LDS dest is linear.
    auto stage = [&](int kt, int buf) {
        char* base = smem + buf * 32768;
        #pragma unroll
        for (int i = 0; i < 4; ++i) {
            int f2 = ((i & 1) << 9) + t;          // chunk id within section, 0..1023
            int keyl = f2 >> 3;
            int c = (f2 & 7) ^ (keyl & 7);
            const half_t* g = (i < 2 ? kh_g : kl_g)
                            + ((size_t)(kt * 128 + keyl)) * H + c * 8;
            gload_lds16(g, base + (i < 2 ? 0 : 16384) + f2 * 16);
        }
    };

    stage(0, 0);

    f32x16 Oa, Ob;
    #pragma unroll
    for (int r = 0; r < 16; ++r) { Oa[r] = 0.f; Ob[r] = 0.f; }
    float lacc = 0.f;

    const int keyl = ksw * 32 + n32;              // this lane's key in the tile
    __syncthreads();

    for (int kt = 0; kt < 32; ++kt) {
        const int cur = kt & 1;

        // V B-frags for the CURRENT tile, direct from global (L2/L1-resident).
        half8 vf00, vf10, vf01, vf11;
        {
            const half_t* vp = vt_g + (size_t)n32 * S + kt * 128 + ksw * 32 + l5 * 8;
            vf00 = *(const half8*)(vp);            // ks2=0, dims 0..31
            vf10 = *(const half8*)(vp + 16);       // ks2=1, dims 0..31
            vf01 = *(const half8*)(vp + 32 * S);   // ks2=0, dims 32..63
            vf11 = *(const half8*)(vp + 32 * S + 16);
        }

        if (kt < 31) stage(kt + 1, cur ^ 1);

        half_t* khs = (half_t*)(smem + cur * 32768);
        half_t* kls = khs + 8192;

        // ---- QK^T swapped: acc = K*Q^T, lane n32 = q-row, regs = keys ----
        f32x16 acc;
        #pragma unroll
        for (int r = 0; r < 16; ++r) acc[r] = 0.f;
        __builtin_amdgcn_s_setprio(1);
        #pragma unroll
        for (int ks = 0; ks < 4; ++ks) {
            int phys = ((ks * 2 + l5) ^ (keyl & 7)) * 8;
            half8 bh = *(const half8*)(khs + keyl * 64 + phys);
            half8 bl = *(const half8*)(kls + keyl * 64 + phys);
            acc = __builtin_amdgcn_mfma_f32_32x32x16_f16(bh, qh[ks], acc, 0, 0, 0);
            acc = __builtin_amdgcn_mfma_f32_32x32x16_f16(bh, ql[ks], acc, 0, 0, 0);
            acc = __builtin_amdgcn_mfma_f32_32x32x16_f16(bl, qh[ks], acc, 0, 0, 0);
        }
        __builtin_amdgcn_s_setprio(0);

        // ---- fixed-max softmax, P stays in registers ----
        // key(r) = (r&3) + 8*(r>>2) + 4*l5  (acc already = qk/8)
        unsigned int h0[4], h1[4];
        #pragma unroll
        for (int m = 0; m < 4; ++m) {
            float p0 = exp2f((floorf(acc[4 * m + 0]) - 8.0f) * LOG2E);
            float p1 = exp2f((floorf(acc[4 * m + 1]) - 8.0f) * LOG2E);
            float p2 = exp2f((floorf(acc[4 * m + 2]) - 8.0f) * LOG2E);
            float p3 = exp2f((floorf(acc[4 * m + 3]) - 8.0f) * LOG2E);
            lacc += p0 + p1 + p2 + p3;
            h0[m] = __builtin_bit_cast(unsigned int, __builtin_amdgcn_cvt_pkrtz(p0, p1));
            h1[m] = __builtin_bit_cast(unsigned int, __builtin_amdgcn_cvt_pkrtz(p2, p3));
        }

        // ---- PV: build A-frags with permlane32_swap, no LDS ----
        __builtin_amdgcn_s_setprio(1);
        #pragma unroll
        for (int ks2 = 0; ks2 < 2; ++ks2) {
            auto s1 = __builtin_amdgcn_permlane32_swap(h0[2 * ks2], h0[2 * ks2 + 1], false, false);
            auto s2 = __builtin_amdgcn_permlane32_swap(h1[2 * ks2], h1[2 * ks2 + 1], false, false);
            uint4v pw;
            pw[0] = s1[0]; pw[1] = s2[0]; pw[2] = s1[1]; pw[3] = s2[1];
            half8 pf = __builtin_bit_cast(half8, pw);
            Oa = __builtin_amdgcn_mfma_f32_32x32x16_f16(pf, ks2 ? vf10 : vf00, Oa, 0, 0, 0);
            Ob = __builtin_amdgcn_mfma_f32_32x32x16_f16(pf, ks2 ? vf11 : vf01, Ob, 0, 0, 0);
        }
        __builtin_amdgcn_s_setprio(0);

        __syncthreads();
    }

    // ---- denominator: other 16 keys live in the opposite lane-half ----
    lacc += __shfl_xor(lacc, 32);

    // ---- combine the 4 key-slice partials via LDS ----
    // Oc [4 ksw][64 rows][64 dims] = 64 KB (stride-64: 2-way writes = free,
    // 4-way epilogue reads, once per block). l_s [4][64] after it.
    float* Oc  = (float*)smem;
    float* l_s = (float*)(smem + 65536);
    #pragma unroll
    for (int r = 0; r < 16; ++r) {
        int rowl = qsub * 32 + (r & 3) + 8 * (r >> 2) + 4 * l5;
        Oc[(ksw * 64 + rowl) * 64 + n32]      = Oa[r];
        Oc[(ksw * 64 + rowl) * 64 + 32 + n32] = Ob[r];
    }
    if (lane < 32) l_s[ksw * 64 + qsub * 32 + n32] = lacc;
    __syncthreads();

    {
        int row = t >> 3;            // 0..63
        int d0 = (t & 7) * 8;        // 0..56
        float den = l_s[row] + l_s[64 + row] + l_s[128 + row] + l_s[192 + row];
        float s0 = 0.f, s1 = 0.f, s2 = 0.f, s3 = 0.f;
        float s4 = 0.f, s5 = 0.f, s6 = 0.f, s7 = 0.f;
        #pragma unroll
        for (int k = 0; k < 4; ++k) {
            const float* oc = Oc + (size_t)(k * 64 + row) * 64 + d0;
            float4 a = *(const float4*)oc;
            float4 bq = *(const float4*)(oc + 4);
            s0 += a.x;  s1 += a.y;  s2 += a.z;  s3 += a.w;
            s4 += bq.x; s5 += bq.y; s6 += bq.z; s7 += bq.w;
        }
        float inv = 1.f / den;
        float4 o1 = make_float4(s0 * inv, s1 * inv, s2 * inv, s3 * inv);
        float4 o2 = make_float4(s4 * inv, s5 * inv, s6 * inv, s7 * inv);
        float* op = out + (size_t)(qrow0 + row) * H + d0;
        *(float4*)op = o1;
        *(float4*)(op + 4) = o2;
    }
}

extern "C" void kernel_launch(void* const* d_in, const int* in_sizes, int n_in,
                              void* d_out, int out_size, void* d_ws, size_t ws_size,
                              hipStream_t stream) {
    const float* x  = (const float*)d_in[0];
    const float* Wq = (const float*)d_in[1];
    const float* Wk = (const float*)d_in[2];
    const float* Wv = (const float*)d_in[3];
    float* outp = (float*)d_out;

    const size_t N = (size_t)B * S * H;          // 1,048,576
    half_t* qhi = (half_t*)d_ws;
    half_t* qlo = qhi + N;
    half_t* khi = qlo + N;
    half_t* klo = khi + N;
    half_t* vt  = klo + N;
    half_t* Wst = vt + N;                        // 294912 halves

    wprep_kernel<<<(3 * H * E) / 256, 256, 0, stream>>>(Wq, Wk, Wv, Wst);
    proj_kernel<<<(B * S) / 32, 512, 0, stream>>>(x, Wst, qhi, qlo, khi, klo, vt);
    flash_kernel<<<B * (S / 64), 512, 0, stream>>>(qhi, qlo, khi, klo, vt, outp);
}